// Round 12
// baseline (177.032 us; speedup 1.0000x reference)
//
#include <hip/hip_runtime.h>
#include <hip/hip_bf16.h>

#define CHN 16
#define RF 9
#define HWDIM 256
#define POSN (HWDIM * HWDIM)
#define NBINS 32768   // 5 bits per axis, 3D Morton
#define TPOS 128      // positions per pack tile

typedef _Float16 half2_t __attribute__((ext_vector_type(2)));

__device__ __forceinline__ half2_t u2h(uint32_t u) {
    union { uint32_t u; half2_t h; } x; x.u = u; return x.h;
}
__device__ __forceinline__ uint32_t f2h(float f) {
    union { _Float16 h; uint16_t u; } x; x.h = (_Float16)f; return (uint32_t)x.u;
}
__device__ __forceinline__ float h2f(uint32_t u) {
    union { uint16_t u; _Float16 h; } x; x.u = (uint16_t)u; return (float)x.h;
}

#if __has_builtin(__builtin_amdgcn_fdot2)
__device__ __forceinline__ float DOT2(half2_t a, half2_t b, float c) {
    return __builtin_amdgcn_fdot2(a, b, c, false);
}
#else
__device__ __forceinline__ float DOT2(half2_t a, half2_t b, float c) {
    return fmaf((float)a.x, (float)b.x, fmaf((float)a.y, (float)b.y, c));
}
#endif

// ---------- Morton helpers ----------
__device__ __forceinline__ uint32_t part1by2(uint32_t x) {
    x &= 0x3ffu;
    x = (x | (x << 16)) & 0x030000FFu;
    x = (x | (x << 8))  & 0x0300F00Fu;
    x = (x | (x << 4))  & 0x030C30C3u;
    x = (x | (x << 2))  & 0x09249249u;
    return x;
}
__device__ __forceinline__ uint32_t morton_key(float c0, float c1, float c2) {
    int q0 = min(31, max(0, (int)((c0 + 1.f) * 16.f)));
    int q1 = min(31, max(0, (int)((c1 + 1.f) * 16.f)));
    int q2 = min(31, max(0, (int)((c2 + 1.f) * 16.f)));
    return (part1by2((uint32_t)q0) << 2) | (part1by2((uint32_t)q1) << 1) | part1by2((uint32_t)q2);
}

// ---------- pack one 128-pos tile, float4 global reads (512B/stream/instr) ----------
// LDS staging layout: LH u16[row=144][pos stride 132] (38 KB). Phase 1: rows read as
// float4 (2 rows x 512B contiguous per wave-instr), converted to f16, stored row-major.
// Phase 2: repack to A [pos][cc] uint4 (r0..r7 pairs) + B [pos][cc>>1] u32 (r8 pairs),
// both dumped with fully coalesced global stores.
__device__ __forceinline__ void pack_tile128(int tile,
                                             const float* __restrict__ Pu,
                                             const float* __restrict__ Pv,
                                             const float* __restrict__ Pw,
                                             uint4* __restrict__ A,
                                             uint32_t* __restrict__ B,
                                             int t, uint32_t* LHw) {
    int p = tile >> 9;                       // 512 tiles per plane
    int pos_base = (tile & 511) * TPOS;
    const float* P = (p == 0) ? Pu : ((p == 1) ? Pv : Pw);
#pragma unroll
    for (int it = 0; it < 18; ++it) {
        int j = it * 256 + t;                // 4608 float4s = 144 rows x 32
        int row = j >> 5;                    // (cc*9 + r) channel-row
        int col = j & 31;                    // positions col*4 .. col*4+3
        const float* rp = P + (size_t)row * POSN + pos_base;
        float4 v = ((const float4*)rp)[col];
        LHw[row * 66 + col * 2 + 0] = f2h(v.x) | (f2h(v.y) << 16);
        LHw[row * 66 + col * 2 + 1] = f2h(v.z) | (f2h(v.w) << 16);
    }
    __syncthreads();
    const unsigned short* LH = (const unsigned short*)LHw;
    uint4* Aout = A + ((size_t)p * POSN + pos_base) * CHN;
#pragma unroll
    for (int it = 0; it < 8; ++it) {
        int i = it * 256 + t;                // 2048 uint4 outputs
        int pos = i >> 4, cc = i & 15;
        const unsigned short* base = LH + (size_t)cc * 9 * 132 + pos;
        uint32_t w0 = (uint32_t)base[0 * 132] | ((uint32_t)base[1 * 132] << 16);
        uint32_t w1 = (uint32_t)base[2 * 132] | ((uint32_t)base[3 * 132] << 16);
        uint32_t w2 = (uint32_t)base[4 * 132] | ((uint32_t)base[5 * 132] << 16);
        uint32_t w3 = (uint32_t)base[6 * 132] | ((uint32_t)base[7 * 132] << 16);
        Aout[i] = make_uint4(w0, w1, w2, w3);
    }
    uint32_t* Bout = B + ((size_t)p * POSN + pos_base) * 8;
#pragma unroll
    for (int it = 0; it < 4; ++it) {
        int i = it * 256 + t;                // 1024 u32 outputs
        int pos = i >> 3, g = i & 7;
        uint32_t lo = LH[((size_t)(2 * g) * 9 + 8) * 132 + pos];
        uint32_t hi = LH[((size_t)(2 * g + 1) * 9 + 8) * 132 + pos];
        Bout[i] = lo | (hi << 16);
    }
}

#define LHW_WORDS (144 * 66)   // 38016 B

// ---------- D1: histogram + pack slice ----------
__global__ __launch_bounds__(256) void fuse_hist(const float* __restrict__ Pu,
                                                 const float* __restrict__ Pv,
                                                 const float* __restrict__ Pw,
                                                 uint4* __restrict__ A,
                                                 uint32_t* __restrict__ B,
                                                 const float* __restrict__ coords,
                                                 uint32_t* __restrict__ hist,
                                                 int N, int npack, int tile_lo) {
    __shared__ uint32_t LHw[LHW_WORDS];
    int b = blockIdx.x, t = threadIdx.x;
    if (b < npack) {
        pack_tile128(tile_lo + b, Pu, Pv, Pw, A, B, t, LHw);
    } else {
        int n = (b - npack) * 256 + t;
        if (n < N) {
            float c0 = coords[3 * n], c1 = coords[3 * n + 1], c2 = coords[3 * n + 2];
            atomicAdd(&hist[morton_key(c0, c1, c2)], 1u);
        }
    }
}

// ---------- D2: 1-block exclusive scan (hidden under pack slice) ----------
__global__ __launch_bounds__(256) void fuse_scan(const float* __restrict__ Pu,
                                                 const float* __restrict__ Pv,
                                                 const float* __restrict__ Pw,
                                                 uint4* __restrict__ A,
                                                 uint32_t* __restrict__ B,
                                                 uint32_t* __restrict__ hist,
                                                 int npack, int tile_lo) {
    __shared__ uint32_t LHw[LHW_WORDS];
    int b = blockIdx.x, t = threadIdx.x;
    if (b == 0) {
        __shared__ uint32_t sh[256];
        const int PER = NBINS / 256;      // 128 bins per thread
        int base = t * PER;
        uint32_t s = 0;
        for (int i = 0; i < PER; ++i) s += hist[base + i];
        sh[t] = s;
        __syncthreads();
        for (int off = 1; off < 256; off <<= 1) {
            uint32_t v = (t >= off) ? sh[t - off] : 0u;
            __syncthreads();
            sh[t] += v;
            __syncthreads();
        }
        uint32_t run = sh[t] - s;         // exclusive prefix of this chunk
        for (int i = 0; i < PER; ++i) {
            uint32_t h = hist[base + i];
            hist[base + i] = run;
            run += h;
        }
    } else {
        pack_tile128(tile_lo + (b - 1), Pu, Pv, Pw, A, B, t, LHw);
    }
}

// ---------- D3: scatter + pack slice ----------
__global__ __launch_bounds__(256) void fuse_scatter(const float* __restrict__ Pu,
                                                    const float* __restrict__ Pv,
                                                    const float* __restrict__ Pw,
                                                    uint4* __restrict__ A,
                                                    uint32_t* __restrict__ B,
                                                    const float* __restrict__ coords,
                                                    uint32_t* __restrict__ hist,
                                                    float4* __restrict__ sorted,
                                                    int N, int npack, int tile_lo) {
    __shared__ uint32_t LHw[LHW_WORDS];
    int b = blockIdx.x, t = threadIdx.x;
    if (b < npack) {
        pack_tile128(tile_lo + b, Pu, Pv, Pw, A, B, t, LHw);
    } else {
        int n = (b - npack) * 256 + t;
        if (n < N) {
            float c0 = coords[3 * n], c1 = coords[3 * n + 1], c2 = coords[3 * n + 2];
            uint32_t key = morton_key(c0, c1, c2);
            uint32_t dst = atomicAdd(&hist[key], 1u);
            sorted[dst] = make_float4(c0, c1, c2, __uint_as_float((uint32_t)n));
        }
    }
}

// ---------- D4: main — EXACT R4 structure (VGPR 36, occupancy ~68%, 84 us) ----------
// 32 points/block, 2 points/thread via outer half-loop (slot, slot+16). meta stride 40.
// meta[pt*40 + p*13 + idx]: [0..3] f16x2 basis r0..7, [4] b8 f32, [5..8] weights f32,
//                           [9..12] corner byte offsets (pos*256)
__global__ __launch_bounds__(256) void triplane_f16v2(const float4* __restrict__ sorted,
                                                      const uint4* __restrict__ A,
                                                      const uint32_t* __restrict__ B,
                                                      float* __restrict__ out, int N, int nblk) {
    __shared__ float4 pts[32];
    __shared__ uint32_t meta[32 * 40];
    int blk = blockIdx.x;
    {   // bijective XCD-chunked swizzle (contiguous Morton range per XCD)
        int q = nblk >> 3, r = nblk & 7;
        int xcd = blk & 7, local = blk >> 3;
        blk = (xcd < r ? xcd * (q + 1) : r * (q + 1) + (xcd - r) * q) + local;
    }
    int base = blk * 32;
    int t = threadIdx.x;
    if (t < 32) {
        int i = base + t;
        pts[t] = (i < N) ? sorted[i] : make_float4(0.f, 0.f, 0.f, __uint_as_float(0u));
    }
    __syncthreads();
    if (t < 128 && (t & 3) < 3) {   // one thread per (point, plane)
        int pt = t >> 2, p = t & 3;
        float4 c = pts[pt];
        float gx = (p == 0) ? c.y : c.x;
        float gy = (p == 2) ? c.y : c.z;
        float ci = (p == 0) ? c.x : ((p == 1) ? c.y : c.z);
        float ix = (gx + 1.f) * 127.5f;
        float iy = (gy + 1.f) * 127.5f;
        float x0f = floorf(ix), y0f = floorf(iy);
        float wx = ix - x0f, wy = iy - y0f;
        int x0 = min(max((int)x0f, 0), HWDIM - 1);
        int y0 = min(max((int)y0f, 0), HWDIM - 1);
        int x1 = min(x0 + 1, HWDIM - 1);
        int y1 = min(y0 + 1, HWDIM - 1);
        uint32_t* m = &meta[pt * 40 + p * 13];
        float cv = (ci + 1.f) * 127.5f + 0.5f;
        float bb[9];
#pragma unroll
        for (int r = 0; r < 9; ++r) {
            const float k = 3.14159265358979f * ((float)(1 << r) - 0.5f) * (1.f / 512.f);
            bb[r] = __cosf(cv * k);
        }
#pragma unroll
        for (int j = 0; j < 4; ++j) m[j] = f2h(bb[2 * j]) | (f2h(bb[2 * j + 1]) << 16);
        m[4] = __float_as_uint(bb[8]);
        m[5] = __float_as_uint((1.f - wx) * (1.f - wy));
        m[6] = __float_as_uint(wx * (1.f - wy));
        m[7] = __float_as_uint((1.f - wx) * wy);
        m[8] = __float_as_uint(wx * wy);
        m[9]  = (uint32_t)(y0 * HWDIM + x0) * 256u;
        m[10] = (uint32_t)(y0 * HWDIM + x1) * 256u;
        m[11] = (uint32_t)(y1 * HWDIM + x0) * 256u;
        m[12] = (uint32_t)(y1 * HWDIM + x1) * 256u;
    }
    __syncthreads();
    int cc = t & 15, slot = t >> 4;
    const char* Ab = (const char*)A;
    const char* Bb = (const char*)B;
    const uint32_t bofs = ((uint32_t)(cc >> 1) << 2);
#pragma unroll
    for (int half = 0; half < 2; ++half) {
        int pt = slot + half * 16;
        int gi = base + pt;
        float acc = 0.f;
#pragma unroll
        for (int p = 0; p < 3; ++p) {
            const uint32_t* m = &meta[pt * 40 + p * 13];
            half2_t b01 = u2h(m[0]), b23 = u2h(m[1]), b45 = u2h(m[2]), b67 = u2h(m[3]);
            float b8 = __uint_as_float(m[4]);
            const char* Apl = Ab + (size_t)p * ((size_t)POSN * 256);
            const char* Bpl = Bb + (size_t)p * ((size_t)POSN * 32);
            float ps = 0.f;
#pragma unroll
            for (int k = 0; k < 4; ++k) {
                uint32_t ob = m[9 + k];
                uint4 a = *(const uint4*)(Apl + ob + cc * 16);    // 16 lanes read 256B contiguous
                uint32_t bw = *(const uint32_t*)(Bpl + (ob >> 3) + bofs);
                float v8 = h2f((cc & 1) ? (bw >> 16) : (bw & 0xffffu));
                float s = b8 * v8;
                s = DOT2(u2h(a.x), b01, s);
                s = DOT2(u2h(a.y), b23, s);
                s = DOT2(u2h(a.z), b45, s);
                s = DOT2(u2h(a.w), b67, s);
                ps = fmaf(__uint_as_float(m[5 + k]), s, ps);
            }
            acc += ps;
        }
        if (gi < N) {
            uint32_t n = __float_as_uint(pts[pt].w);
            out[(size_t)n * CHN + cc] = 2.f * acc;
        }
    }
}

// ---------- fallback: direct gather from (C,H,W) f32 ----------
__global__ __launch_bounds__(256) void triplane_direct(const float* __restrict__ coords,
                                                       const float* __restrict__ Pu,
                                                       const float* __restrict__ Pv,
                                                       const float* __restrict__ Pw,
                                                       float* __restrict__ out, int N) {
    int tid = blockIdx.x * blockDim.x + threadIdx.x;
    int n = tid >> 4;
    if (n >= N) return;
    int cc = tid & 15;
    float c0 = coords[3 * n + 0];
    float c1 = coords[3 * n + 1];
    float c2 = coords[3 * n + 2];
    float acc = 0.f;
#pragma unroll
    for (int p = 0; p < 3; ++p) {
        const float* P = (p == 0) ? Pu : ((p == 1) ? Pv : Pw);
        float gx = (p == 0) ? c1 : c0;
        float gy = (p == 2) ? c1 : c2;
        float ci = (p == 0) ? c0 : ((p == 1) ? c1 : c2);
        float ix = (gx + 1.f) * 127.5f;
        float iy = (gy + 1.f) * 127.5f;
        float x0f = floorf(ix), y0f = floorf(iy);
        float wx = ix - x0f, wy = iy - y0f;
        int x0 = min(max((int)x0f, 0), HWDIM - 1);
        int y0 = min(max((int)y0f, 0), HWDIM - 1);
        int x1 = min(x0 + 1, HWDIM - 1);
        int y1 = min(y0 + 1, HWDIM - 1);
        float cv = (ci + 1.f) * 127.5f + 0.5f;
        float w00 = (1.f - wx) * (1.f - wy), w01 = wx * (1.f - wy);
        float w10 = (1.f - wx) * wy, w11 = wx * wy;
        int p00 = y0 * HWDIM + x0, p01 = y0 * HWDIM + x1;
        int p10 = y1 * HWDIM + x0, p11 = y1 * HWDIM + x1;
#pragma unroll
        for (int r = 0; r < RF; ++r) {
            const float k = 3.14159265358979f * ((float)(1 << r) - 0.5f) / 512.f;
            float b = __cosf(cv * k);
            const float* Pc = P + (size_t)(cc * RF + r) * POSN;
            float v = w00 * Pc[p00] + w01 * Pc[p01] + w10 * Pc[p10] + w11 * Pc[p11];
            acc = fmaf(b, v, acc);
        }
    }
    out[(size_t)n * CHN + cc] = 2.f * acc;
}

extern "C" void kernel_launch(void* const* d_in, const int* in_sizes, int n_in,
                              void* d_out, int out_size, void* d_ws, size_t ws_size,
                              hipStream_t stream) {
    const float* coords = (const float*)d_in[0];
    const float* Pu = (const float*)d_in[1];
    const float* Pv = (const float*)d_in[2];
    const float* Pw = (const float*)d_in[3];
    float* out = (float*)d_out;
    int N = in_sizes[0] / 3;

    size_t offA = 0;
    size_t szA = (size_t)3 * POSN * CHN * sizeof(uint4);        // 48 MB
    size_t offB = offA + szA;
    size_t szB = (size_t)3 * POSN * 8 * sizeof(uint32_t);       // 6 MB
    size_t offS = offB + szB;
    size_t szS = (size_t)N * sizeof(float4);                    // 8 MB @ N=524288
    size_t offH = offS + szS;
    size_t szH = (size_t)NBINS * sizeof(uint32_t);              // 128 KB
    size_t need = offH + szH;

    if (ws_size >= need) {
        char* ws = (char*)d_ws;
        uint4* A = (uint4*)(ws + offA);
        uint32_t* B = (uint32_t*)(ws + offB);
        float4* sorted = (float4*)(ws + offS);
        uint32_t* hist = (uint32_t*)(ws + offH);

        int tblk = (3 * POSN) / TPOS;                // 1536 pack tiles (128 pos each)
        int s1 = tblk / 3;                           // 512
        int s2 = tblk / 3;                           // 512
        int s3 = tblk - s1 - s2;                     // 512
        int hblk = (N + 255) / 256;                  // 2048

        hipMemsetAsync(hist, 0, szH, stream);
        fuse_hist<<<s1 + hblk, 256, 0, stream>>>(Pu, Pv, Pw, A, B, coords, hist, N, s1, 0);
        fuse_scan<<<1 + s2, 256, 0, stream>>>(Pu, Pv, Pw, A, B, hist, s2, s1);
        fuse_scatter<<<s3 + hblk, 256, 0, stream>>>(Pu, Pv, Pw, A, B, coords, hist, sorted,
                                                    N, s3, s1 + s2);
        int nblk = (N + 31) / 32;                    // 16384
        triplane_f16v2<<<nblk, 256, 0, stream>>>(sorted, A, B, out, N, nblk);
    } else {
        int threads = N * CHN;
        triplane_direct<<<(threads + 255) / 256, 256, 0, stream>>>(coords, Pu, Pv, Pw, out, N);
    }
}